// Round 3
// baseline (386.521 us; speedup 1.0000x reference)
//
#include <hip/hip_runtime.h>
#include <hip/hip_bf16.h>

#define GD 64
#define GC 256

typedef unsigned short u16;
typedef unsigned int u32;
typedef unsigned long long u64;
typedef short bf16x8 __attribute__((ext_vector_type(8)));
typedef float f32x4 __attribute__((ext_vector_type(4)));

__device__ __forceinline__ u16 f2bf_rne(float f) {
    u32 u = __builtin_bit_cast(u32, f);
    u = (u + 0x7FFFu + ((u >> 16) & 1u)) >> 16;
    return (u16)u;
}

// ---------------------------------------------------------------- weight prep (+ mask zero)
// img1: 2 halves x [nn(64)][chunk(32)^swz][j(8)]  <- W1[k=chunk*8+j][h*64+nn]
// img2: 2 halves x [nn(128)][chunk(16)^swz][j(8)] <- W2[k=chunk*8+j][h*128+nn]
__global__ __launch_bounds__(256) void prep_weights(const float* __restrict__ W1,
        const float* __restrict__ W2, u16* __restrict__ img1, u16* __restrict__ img2,
        u64* __restrict__ maskZ) {
    int t = blockIdx.x * 256 + threadIdx.x;   // 0..65535
    if (t < 4096) maskZ[t] = 0ull;
    if (t < 32768) {
        int h = t >> 14, nn = (t >> 8) & 63, chunk = (t >> 3) & 31, j = t & 7;
        int k = chunk * 8 + j;
        img1[(h << 14) + nn * 256 + (((chunk ^ (nn & 7)) << 3) | j)] =
            f2bf_rne(W1[k * 128 + h * 64 + nn]);
    } else {
        int t2 = t - 32768;
        int h = t2 >> 14, nn = (t2 >> 7) & 127, chunk = (t2 >> 3) & 15, j = t2 & 7;
        int k = chunk * 8 + j;
        img2[(h << 14) + nn * 128 + (((chunk ^ (nn & 7)) << 3) | j)] =
            f2bf_rne(W2[k * 256 + h * 128 + nn]);
    }
}

// ---------------------------------------------------------------- scatter (+ occupancy mask)
__global__ __launch_bounds__(256) void scatter_feats(const float* __restrict__ feats,
        const int* __restrict__ coords, u16* __restrict__ gridA,
        u64* __restrict__ maskZ, int n) {
    int t = blockIdx.x * 256 + threadIdx.x;
    int i = t >> 5;
    if (i >= n) return;
    int c8 = (t & 31) << 3;
    int ix = coords[3 * i], iy = coords[3 * i + 1], iz = coords[3 * i + 2];
    if ((t & 31) == 0) atomicOr(&maskZ[ix * GD + iy], 1ull << iz);
    size_t cell = (size_t)((ix * GD + iy) * GD + iz);
    const float4* src = (const float4*)(feats + (size_t)i * GC + c8);
    float4 a = src[0], b = src[1];
    u32 p0 = (u32)f2bf_rne(a.x) | ((u32)f2bf_rne(a.y) << 16);
    u32 p1 = (u32)f2bf_rne(a.z) | ((u32)f2bf_rne(a.w) << 16);
    u32 p2 = (u32)f2bf_rne(b.x) | ((u32)f2bf_rne(b.y) << 16);
    u32 p3 = (u32)f2bf_rne(b.z) | ((u32)f2bf_rne(b.w) << 16);
    *(uint4*)(gridA + cell * GC + c8) = make_uint4(p0, p1, p2, p3);
}

// ---------------------------------------------------------------- pool pass (ping-pong)
// Rolling 7-window, 8 channels/thread (uint4). src != dst (__restrict__) so the
// compiler can run loads ahead of stores. MASKED: first pass reads only
// occupied cells (scatter buffer is uninitialized elsewhere) and writes dense.
__device__ __forceinline__ void unpack8(uint4 r, float* w) {
    u32 v[4] = {r.x, r.y, r.z, r.w};
#pragma unroll
    for (int i = 0; i < 4; i++) {
        w[2 * i]     = __builtin_bit_cast(float, v[i] << 16);
        w[2 * i + 1] = __builtin_bit_cast(float, v[i] & 0xFFFF0000u);
    }
}

template<bool MASKED>
__global__ __launch_bounds__(256, 2) void pool_pass_pp(const u16* __restrict__ src,
        u16* __restrict__ dst, const u64* __restrict__ maskZ,
        int mulA, int mulB, int strideCell) {
    int chunk = threadIdx.x & 31;
    int L = blockIdx.x * 8 + (threadIdx.x >> 5);   // 0..4095
    int a = L >> 6, b = L & 63;
    size_t baseEl = ((size_t)a * mulA + (size_t)b * mulB) * GC + chunk * 8;
    size_t stepEl = (size_t)strideCell * GC;
    const u16* ps = src + baseEl;
    u16* pd = dst + baseEl;
    u64 m = MASKED ? maskZ[L] : 0ull;   // z-pass: L = x*64+y, matches mask index

    float win[7][8];
#pragma unroll
    for (int s = 0; s < 7; s++)
#pragma unroll
        for (int c = 0; c < 8; c++) win[s][c] = -INFINITY;

#pragma unroll
    for (int t = 0; t < 3; t++) {   // preload in[0..2] -> slots 3..5
        if (!MASKED || ((m >> t) & 1)) {
            uint4 r = *(const uint4*)(ps + (size_t)t * stepEl);
            unpack8(r, win[t + 3]);
        }
    }

#pragma unroll
    for (int z = 0; z < 64; z++) {
        int slot = (z + 6) % 7;     // in[z+3] replaces in[z-4]
        bool ld = (z + 3 < 64) && (!MASKED || ((m >> (z + 3)) & 1));
        if (ld) {
            uint4 r = *(const uint4*)(ps + (size_t)(z + 3) * stepEl);
            unpack8(r, win[slot]);
        } else {
#pragma unroll
            for (int c = 0; c < 8; c++) win[slot][c] = -INFINITY;
        }
        u32 q[4];
#pragma unroll
        for (int i = 0; i < 4; i++) {
            u32 halves[2];
#pragma unroll
            for (int hh = 0; hh < 2; hh++) {
                int c = 2 * i + hh;
                float m01 = fmaxf(win[0][c], win[1][c]);
                float m23 = fmaxf(win[2][c], win[3][c]);
                float m45 = fmaxf(win[4][c], win[5][c]);
                float mx = fmaxf(fmaxf(m01, m23), fmaxf(m45, win[6][c]));
                halves[hh] = __builtin_bit_cast(u32, mx);   // exact bf16 value
            }
            q[i] = (halves[0] >> 16) | (halves[1] & 0xFFFF0000u);
        }
        *(uint4*)(pd + (size_t)z * stepEl) = make_uint4(q[0], q[1], q[2], q[3]);
    }
}

// ---------------------------------------------------------------- GEMM1 (half-N)
__global__ __launch_bounds__(256, 4) void gemm1_kernel(const u16* __restrict__ grid,
        const int* __restrict__ coords, const u16* __restrict__ img1,
        u16* __restrict__ H, int n, int nrb) {
    __shared__ __align__(16) u16 w1t[64 * 256];   // 32768 B; reused as hbuf
    int h = blockIdx.x >= nrb;
    int rb = blockIdx.x - (h ? nrb : 0);
    int tid = threadIdx.x;

    const uint4* src = (const uint4*)(img1 + (h << 14));
    uint4* dst = (uint4*)w1t;
#pragma unroll
    for (int i = 0; i < 8; i++) dst[i * 256 + tid] = src[i * 256 + tid];

    int wave = tid >> 6, lane = tid & 63, m16 = lane & 15, quad = lane >> 4;
    int row_a = rb * 64 + wave * 16 + m16;
    int ra = min(row_a, n - 1);
    int ix = coords[3 * ra], iy = coords[3 * ra + 1], iz = coords[3 * ra + 2];
    const u16* yrow = grid + (size_t)((ix * GD + iy) * GD + iz) * GC;
    bf16x8 afr[8];
#pragma unroll
    for (int kk = 0; kk < 8; kk++)
        afr[kk] = *(const bf16x8*)(yrow + kk * 32 + quad * 8);
    __syncthreads();

    f32x4 acc[4];
#pragma unroll
    for (int t = 0; t < 4; t++) acc[t] = (f32x4){0.f, 0.f, 0.f, 0.f};
#pragma unroll
    for (int kk = 0; kk < 8; kk++) {
        int chunk = kk * 4 + quad;
#pragma unroll
        for (int t = 0; t < 4; t++) {
            int r = t * 16 + m16;
            bf16x8 b = *(const bf16x8*)&w1t[r * 256 + ((chunk ^ (r & 7)) << 3)];
            acc[t] = __builtin_amdgcn_mfma_f32_16x16x32_bf16(afr[kk], b, acc[t], 0, 0, 0);
        }
    }
    __syncthreads();   // w1t dead; reuse as hbuf [row(64)][c8^swz][j]

    u16* hbuf = w1t;
#pragma unroll
    for (int t = 0; t < 4; t++) {
        int col = t * 16 + m16;
        int c8 = col >> 3, j = col & 7;
#pragma unroll
        for (int rr = 0; rr < 4; rr++) {
            int row_l = wave * 16 + quad * 4 + rr;
            float hv = fmaxf(acc[t][rr], 0.0f);
            hbuf[row_l * 64 + (((c8 ^ (row_l & 7)) << 3) | j)] = f2bf_rne(hv);
        }
    }
    __syncthreads();
#pragma unroll
    for (int i = 0; i < 2; i++) {
        int cid = i * 256 + tid;            // 0..511 chunks of 8
        int row_l = cid >> 3, c8 = cid & 7;
        int grow = rb * 64 + row_l;
        if (grow < n) {
            bf16x8 v = *(const bf16x8*)&hbuf[row_l * 64 + ((c8 ^ (row_l & 7)) << 3)];
            *(bf16x8*)&H[(size_t)grow * 128 + h * 64 + c8 * 8] = v;
        }
    }
}

// ---------------------------------------------------------------- GEMM2 (half-N)
__global__ __launch_bounds__(256, 4) void gemm2_kernel(const u16* __restrict__ H,
        const u16* __restrict__ img2, const float* __restrict__ feats,
        float* __restrict__ out, int n, int nrb) {
    __shared__ __align__(16) char smem[64 * 140 * 4];   // 35840 B
    u16* w2t = (u16*)smem;          // 32768 B used
    float* zbuf = (float*)smem;     // 64 x 140 f32
    int h = blockIdx.x >= nrb;
    int rb = blockIdx.x - (h ? nrb : 0);
    int tid = threadIdx.x;

    const uint4* src = (const uint4*)(img2 + (h << 14));
    uint4* dst = (uint4*)w2t;
#pragma unroll
    for (int i = 0; i < 8; i++) dst[i * 256 + tid] = src[i * 256 + tid];

    int wave = tid >> 6, lane = tid & 63, m16 = lane & 15, quad = lane >> 4;
    int row_a = rb * 64 + wave * 16 + m16;
    int ra = min(row_a, n - 1);
    const u16* hrow = H + (size_t)ra * 128;
    bf16x8 afr[4];
#pragma unroll
    for (int kk = 0; kk < 4; kk++)
        afr[kk] = *(const bf16x8*)(hrow + kk * 32 + quad * 8);
    __syncthreads();

    f32x4 acc[8];
#pragma unroll
    for (int t = 0; t < 8; t++) acc[t] = (f32x4){0.f, 0.f, 0.f, 0.f};
#pragma unroll
    for (int kk = 0; kk < 4; kk++) {
        int chunk = kk * 4 + quad;
#pragma unroll
        for (int t = 0; t < 8; t++) {
            int nn = t * 16 + m16;
            bf16x8 b = *(const bf16x8*)&w2t[nn * 128 + ((chunk ^ (nn & 7)) << 3)];
            acc[t] = __builtin_amdgcn_mfma_f32_16x16x32_bf16(afr[kk], b, acc[t], 0, 0, 0);
        }
    }
    __syncthreads();   // w2t dead; write logits into zbuf

#pragma unroll
    for (int t = 0; t < 8; t++) {
        int col = t * 16 + m16;
#pragma unroll
        for (int rr = 0; rr < 4; rr++) {
            int row_l = wave * 16 + quad * 4 + rr;
            zbuf[row_l * 140 + col] = acc[t][rr];
        }
    }
    __syncthreads();
#pragma unroll
    for (int i = 0; i < 8; i++) {
        int f = i * 256 + tid;              // 0..2047 float4s
        int row_l = f >> 5, c4 = f & 31;
        int grow = rb * 64 + row_l;
        if (grow < n) {
            f32x4 z = *(const f32x4*)&zbuf[row_l * 140 + c4 * 4];
            size_t o = (size_t)grow * 256 + h * 128 + c4 * 4;
            f32x4 ft = *(const f32x4*)&feats[o];
            f32x4 r;
#pragma unroll
            for (int c = 0; c < 4; c++)
                r[c] = ft[c] / (1.0f + __expf(-z[c]));
            *(f32x4*)&out[o] = r;
        }
    }
}

// ---------------------------------------------------------------- launch
extern "C" void kernel_launch(void* const* d_in, const int* in_sizes, int n_in,
                              void* d_out, int out_size, void* d_ws, size_t ws_size,
                              hipStream_t stream) {
    const float* feats = (const float*)d_in[0];
    const int* coords = (const int*)d_in[1];
    const float* W1 = (const float*)d_in[2];
    const float* W2 = (const float*)d_in[3];
    float* out = (float*)d_out;

    int n = in_sizes[1] / 3;                       // 100000 points

    size_t grid_bytes = (size_t)GD * GD * GD * GC * 2;          // 134,217,728
    u16* A = (u16*)d_ws;                                        // scatter + y-out
    u16* B = (u16*)((char*)d_ws + grid_bytes);                  // z-out + x-out
    char* p = (char*)d_ws + 2 * grid_bytes;
    u16* H = (u16*)p;                   p += (size_t)n * 128 * 2;
    u16* img1 = (u16*)p;                p += 65536 * 2;          // 2x32768 u16
    u16* img2 = (u16*)p;                p += 65536 * 2;
    u64* maskZ = (u64*)p;                                        // 4096 u64

    prep_weights<<<256, 256, 0, stream>>>(W1, W2, img1, img2, maskZ);

    scatter_feats<<<(n * 32 + 255) / 256, 256, 0, stream>>>(feats, coords, A, maskZ, n);

    // separable 7-wide max pool, ping-pong: z (masked) A->B, y B->A, x A->B
    pool_pass_pp<true ><<<512, 256, 0, stream>>>(A, B, maskZ, GD * GD, GD, 1);   // z
    pool_pass_pp<false><<<512, 256, 0, stream>>>(B, A, maskZ, GD * GD, 1, GD);   // y
    pool_pass_pp<false><<<512, 256, 0, stream>>>(A, B, maskZ, GD, 1, GD * GD);   // x

    int nrb = (n + 63) / 64;
    gemm1_kernel<<<2 * nrb, 256, 0, stream>>>(B, coords, img1, H, n, nrb);
    gemm2_kernel<<<2 * nrb, 256, 0, stream>>>(H, img2, feats, out, n, nrb);
}